// Round 9
// baseline (495.394 us; speedup 1.0000x reference)
//
#include <hip/hip_runtime.h>
#include <hip/hip_bf16.h>
#include <stdint.h>

// Problem dims (fixed)
constexpr int BDIM = 8192;
constexpr int INDIM = 4096;
constexpr int OUTDIM = 4096;

typedef __attribute__((ext_vector_type(8))) short bf16x8;
typedef __attribute__((ext_vector_type(8))) short short8;
typedef __attribute__((ext_vector_type(4))) float f32x4;

__device__ __forceinline__ uint16_t f2bf_rne(float f) {
  union { float f; uint32_t u; } v; v.f = f;
  uint32_t r = v.u + 0x7fffu + ((v.u >> 16) & 1u);
  return (uint16_t)(r >> 16);
}
__device__ __forceinline__ float bf2f(uint16_t h) {
  union { uint32_t u; float f; } v; v.u = ((uint32_t)h) << 16; return v.f;
}

__device__ __forceinline__ void gload_lds16(const void* g, void* l) {
  __builtin_amdgcn_global_load_lds(
      (const __attribute__((address_space(1))) void*)g,
      (__attribute__((address_space(3))) void*)l, 16, 0, 0);
}

// ---------------- kernel 1: fused pre-pass (L2-amplification fixed) ----------
// blocks 0..511   : x -> bf16 + haar, 16 rows/block, proj_w[0:5] staged in LDS
// blocks 512..1023: lin_w -> bf16 (grid-stride)
// block  1024     : db scalars -> cvec[4096], W5[5][4096]
__global__ __launch_bounds__(256) void k_pre(
    const float* __restrict__ x, const float* __restrict__ lin_w,
    const float* __restrict__ proj_w, const float* __restrict__ proj_b,
    const float* __restrict__ scales, const float* __restrict__ trans,
    const float* __restrict__ lin_b, const float* __restrict__ comb_w,
    const float* __restrict__ comb_b, uint16_t* __restrict__ xb,
    uint16_t* __restrict__ wb, float* __restrict__ haar,
    float* __restrict__ cvec, float* __restrict__ W5) {
  __shared__ float pj[5 * 4096];  // exactly 80 KiB -> 2 blocks/CU
  const int tid = threadIdx.x;
  const int lane = tid & 63, w = tid >> 6;

  if (blockIdx.x < 512) {
    // ---- stage proj_w rows 0..4 into LDS (once per block) ----
    float4* pj4 = (float4*)pj;
    const float4* pw4 = (const float4*)proj_w;
    for (int i = tid; i < 5 * 1024; i += 256) pj4[i] = pw4[i];
    __syncthreads();
    const int row0 = blockIdx.x * 16 + w * 4;  // one wave owns 4 rows
    for (int rr = 0; rr < 4; ++rr) {
      const int row = row0 + rr;
      const float4* xr = (const float4*)(x + (size_t)row * INDIM);
      ushort4* xbr = (ushort4*)(xb + (size_t)row * INDIM);
      float a[5] = {0.f, 0.f, 0.f, 0.f, 0.f};
#pragma unroll
      for (int k = 0; k < 16; ++k) {
        int i4 = lane + k * 64;            // coalesced, 16B/lane
        float4 v = xr[i4];
        ushort4 o;
        o.x = f2bf_rne(v.x); o.y = f2bf_rne(v.y);
        o.z = f2bf_rne(v.z); o.w = f2bf_rne(v.w);
        xbr[i4] = o;
#pragma unroll
        for (int j = 0; j < 5; ++j) {
          float4 p = pj4[j * 1024 + i4];   // LDS, conflict-free b128
          a[j] += v.x * p.x + v.y * p.y + v.z * p.z + v.w * p.w;
        }
      }
#pragma unroll
      for (int j = 0; j < 5; ++j) {
#pragma unroll
        for (int off = 32; off; off >>= 1) a[j] += __shfl_down(a[j], off, 64);
      }
      if (lane == 0) {
#pragma unroll
        for (int j = 0; j < 5; ++j) {
          float p = a[j] + proj_b[j];
          float sx = (p - trans[j]) / scales[j];
          float h = 0.f;
          if (sx >= 0.f && sx < 0.5f) h = 1.f;
          else if (sx >= 0.5f && sx < 1.f) h = -1.f;
          haar[(size_t)row * 5 + j] = h;
        }
      }
    }
  } else if (blockIdx.x < 1024) {
    // ---- lin_w -> bf16 ----
    const int bid = blockIdx.x - 512;
    const int n8 = (OUTDIM * INDIM) / 8;
    const float4* w4 = (const float4*)lin_w;
    short8* wb8 = (short8*)wb;
    for (int i = bid * 256 + tid; i < n8; i += 512 * 256) {
      float4 v0 = w4[i * 2];
      float4 v1 = w4[i * 2 + 1];
      short8 o;
      o[0] = (short)f2bf_rne(v0.x); o[1] = (short)f2bf_rne(v0.y);
      o[2] = (short)f2bf_rne(v0.z); o[3] = (short)f2bf_rne(v0.w);
      o[4] = (short)f2bf_rne(v1.x); o[5] = (short)f2bf_rne(v1.y);
      o[6] = (short)f2bf_rne(v1.z); o[7] = (short)f2bf_rne(v1.w);
      wb8[i] = o;
    }
  } else {
    // ---- db scalars -> cvec, W5 (single block; reuse pj as scratch) ----
    float* wred = pj;        // [4][11]
    float* dbs = pj + 64;    // [11]
    float acc[11];
#pragma unroll
    for (int j = 0; j < 11; ++j) acc[j] = 0.f;
    for (int r = 0; r < 4; ++r) {
      const float4* xr = (const float4*)(x + (size_t)r * INDIM);
      for (int c = tid; c < INDIM / 4; c += 256) {
        float4 v = xr[c];
#pragma unroll
        for (int j = 0; j < 11; ++j) {
          float4 p = ((const float4*)(proj_w + (size_t)(j + 5) * INDIM))[c];
          acc[j] += v.x * p.x + v.y * p.y + v.z * p.z + v.w * p.w;
        }
      }
    }
#pragma unroll
    for (int j = 0; j < 11; ++j) {
      float v = acc[j];
#pragma unroll
      for (int off = 32; off; off >>= 1) v += __shfl_down(v, off, 64);
      if (lane == 0) wred[w * 11 + j] = v;
    }
    __syncthreads();
    if (tid == 0) {
      const float DB2[4] = {-0.1294095225512604f, -0.2241438680420134f,
                            0.8365163037378079f, -0.4829629131445341f};
      const float DB4[8] = {-0.0074578275060427f, -0.0233534968567756f,
                            0.0218081502370024f,  0.1323683939878645f,
                            -0.0197721859913265f, -0.4461007108737368f,
                            0.5055922216746659f,  -0.1629171572809054f};
      for (int j = 0; j < 11; ++j) {
        float sum = wred[0 * 11 + j] + wred[1 * 11 + j] + wred[2 * 11 + j] +
                    wred[3 * 11 + j];
        float val = sum * 0.25f + proj_b[j + 5];
        float sc = scales[j + 5];
        float sf = 2.f / (1.f + expf(-sc));
        const float* filt = (j < 5) ? DB2 : DB4;
        int L = (j < 5) ? 4 : 8;
        float ssin = 0.f, sabs = 0.f;
        for (int i = 0; i < L; ++i) {
          float fi = filt[i] * sf;
          ssin += sinf(fi * 5.0f);
          sabs += fabsf(fi);
        }
        dbs[j] = val * (ssin / (float)L) / (sabs * 0.1f);
      }
    }
    __syncthreads();
    for (int o = tid; o < OUTDIM; o += 256) {
      const float* cw = comb_w + (size_t)o * 16;
      float cc = lin_b[o] + comb_b[o];
#pragma unroll
      for (int j = 0; j < 11; ++j) cc += dbs[j] * cw[5 + j];
      cvec[o] = cc;
#pragma unroll
      for (int j = 0; j < 5; ++j) W5[j * OUTDIM + o] = cw[j];
    }
  }
}

// ---------------- kernel 4: bf16 MFMA GEMM, 256x256 8-phase (R4 core, FROZEN) ----
// Template WB: epilogue writes bf16 y to Ybf (ws) instead of fp32 to C.

#define BARX() __builtin_amdgcn_s_barrier()
#define LGKM0() do { asm volatile("s_waitcnt lgkmcnt(0)" ::: "memory"); \
                     __builtin_amdgcn_sched_barrier(0); } while (0)
#define VM6() asm volatile("s_waitcnt vmcnt(6)" ::: "memory")

#define STAGE_A(t, q) do { \
  const char* _s = aSrc + (size_t)(q) * 64 * 8192 + (size_t)((t) & 63) * 128; \
  char* _l = sA + ((t) & 1) * 32768 + (q) * 8192 + ldsStage; \
  gload_lds16(_s, _l); gload_lds16(_s + 128 * 8192, _l + 16384); } while (0)

#define STAGE_B(t, h) do { \
  const char* _s = bSrc + (size_t)(h) * 128 * 8192 + (size_t)((t) & 63) * 128; \
  char* _l = sB + ((t) & 1) * 32768 + (h) * 16384 + ldsStage; \
  gload_lds16(_s, _l); gload_lds16(_s + 64 * 8192, _l + 8192); } while (0)

#define RDA4(buf, mb) do { const char* _p = sA + (buf) * 32768; \
  _Pragma("unroll") for (int _m = 0; _m < 4; ++_m) { \
    ar[_m][0] = *(const bf16x8*)(_p + (aoff + ((mb) + _m) * 2048)); \
    ar[_m][1] = *(const bf16x8*)(_p + ((aoff ^ 64) + ((mb) + _m) * 2048)); } } while (0)

#define RDB2(buf, arr, nb) do { const char* _p = sB + (buf) * 32768; \
  _Pragma("unroll") for (int _n = 0; _n < 2; ++_n) { \
    arr[_n][0] = *(const bf16x8*)(_p + (boff + ((nb) + _n) * 2048)); \
    arr[_n][1] = *(const bf16x8*)(_p + ((boff ^ 64) + ((nb) + _n) * 2048)); } } while (0)

#define MF8(mb, arrB, nb) do { \
  __builtin_amdgcn_s_setprio(1); \
  _Pragma("unroll") for (int _m = 0; _m < 4; ++_m) \
  _Pragma("unroll") for (int _n = 0; _n < 2; ++_n) { \
    acc[(mb) + _m][(nb) + _n] = __builtin_amdgcn_mfma_f32_16x16x32_bf16( \
        ar[_m][0], arrB[_n][0], acc[(mb) + _m][(nb) + _n], 0, 0, 0); \
    acc[(mb) + _m][(nb) + _n] = __builtin_amdgcn_mfma_f32_16x16x32_bf16( \
        ar[_m][1], arrB[_n][1], acc[(mb) + _m][(nb) + _n], 0, 0, 0); } \
  __builtin_amdgcn_s_setprio(0); } while (0)

template <bool WB>
__global__ __launch_bounds__(512, 2) void k_gemm(const uint16_t* __restrict__ A,
                                                 const uint16_t* __restrict__ Bw,
                                                 float* __restrict__ C,
                                                 uint16_t* __restrict__ Ybf) {
  constexpr int K = INDIM;   // 4096, row = 8192 bytes
  constexpr int N = OUTDIM;  // 4096
  extern __shared__ char smem[];
  char* sA = smem;
  char* sB = smem + 65536;

  const int tid = threadIdx.x;
  const int wid = tid >> 6;
  const int lane = tid & 63;
  const int l15 = lane & 15;
  const int kh = lane >> 4;
  const int wm = wid >> 2;
  const int wn = wid & 3;

  const int nwg = gridDim.x;
  const int bid = blockIdx.x;
  const int wg = (bid & 7) * (nwg >> 3) + (bid >> 3);
  constexpr int NBN = N / 256;
  const int mblk = wg / NBN, nblk = wg % NBN;
  const size_t arow = (size_t)mblk * 256, brow = (size_t)nblk * 256;

  const int srow = tid >> 3;
  const int scol = ((tid & 7) * 16) ^ ((srow & 7) << 4);
  const char* aSrc = (const char*)A + (arow + srow) * 8192 + scol;
  const char* bSrc = (const char*)Bw + (brow + srow) * 8192 + scol;
  const int ldsStage = wid * 1024;

  const int col0 = (kh * 16) ^ ((l15 & 7) << 4);
  const int aoff = (wm * 128 + l15) * 128 + col0;
  const int boff = (wn * 64 + l15) * 128 + col0;

  f32x4 acc[8][4];
#pragma unroll
  for (int m = 0; m < 8; ++m)
#pragma unroll
    for (int n = 0; n < 4; ++n) acc[m][n] = (f32x4){0.f, 0.f, 0.f, 0.f};
  bf16x8 ar[4][2], b01[2][2], b23[2][2];

  STAGE_A(0, 0); STAGE_A(0, 1); STAGE_B(0, 0); STAGE_B(0, 1);
  STAGE_A(1, 0); STAGE_B(1, 0); STAGE_B(1, 1);
  VM6(); BARX();

  for (int it = 0; it < K / 128; ++it) {
    const int t1 = it * 2 + 1, t2 = it * 2 + 2, t3 = it * 2 + 3;
    // P1
    RDA4(0, 0); RDB2(0, b01, 0);
    STAGE_A(t1, 1);
    BARX(); LGKM0(); MF8(0, b01, 0); BARX();
    // P2
    RDB2(0, b23, 2);
    STAGE_A(t2, 0);
    BARX(); LGKM0(); MF8(0, b23, 2); BARX();
    // P3
    RDA4(0, 4);
    STAGE_B(t2, 0);
    BARX(); LGKM0(); MF8(4, b01, 0); BARX();
    // P4
    STAGE_B(t2, 1);
    BARX(); LGKM0(); MF8(4, b23, 2);
    VM6(); BARX();
    // P5
    RDA4(1, 0); RDB2(1, b01, 0);
    STAGE_A(t2, 1);
    BARX(); LGKM0(); MF8(0, b01, 0); BARX();
    // P6
    RDB2(1, b23, 2);
    STAGE_A(t3, 0);
    BARX(); LGKM0(); MF8(0, b23, 2); BARX();
    // P7
    RDA4(1, 4);
    STAGE_B(t3, 0);
    BARX(); LGKM0(); MF8(4, b01, 0); BARX();
    // P8
    STAGE_B(t3, 1);
    BARX(); LGKM0(); MF8(4, b23, 2);
    VM6(); BARX();
  }

  // epilogue: C/D layout col=lane&15, row=(lane>>4)*4+reg (m89-verified)
  const size_t crow0 = arow + (size_t)wm * 128;
  const int ccol0 = (int)brow + wn * 64;
#pragma unroll
  for (int m = 0; m < 8; ++m) {
#pragma unroll
    for (int n = 0; n < 4; ++n) {
      if constexpr (WB) {
        uint16_t* yp = Ybf + (crow0 + m * 16 + kh * 4) * (size_t)N
                       + ccol0 + n * 16 + l15;
#pragma unroll
        for (int j = 0; j < 4; ++j) yp[(size_t)j * N] = f2bf_rne(acc[m][n][j]);
      } else {
        float* cp = C + (crow0 + m * 16 + kh * 4) * N + ccol0 + n * 16 + l15;
#pragma unroll
        for (int j = 0; j < 4; ++j) cp[(size_t)j * N] = acc[m][n][j];
      }
    }
  }
}

// ---------------- kernel 5: wave-path add + LayerNorm (W5 in LDS, wave/row) ----
// RB: read y as bf16 (ushort4, coalesced); !RB: fp32 from out.
template <bool RB>
__global__ __launch_bounds__(256) void k_ln(
    float* __restrict__ out, const uint16_t* __restrict__ ybf,
    const float* __restrict__ haar, const float* __restrict__ cvec,
    const float* __restrict__ W5, const float* __restrict__ g,
    const float* __restrict__ beta) {
  __shared__ float w5l[5 * 4096];  // exactly 80 KiB -> 2 blocks/CU
  const int tid = threadIdx.x, lane = tid & 63, w = tid >> 6;
  float4* w54 = (float4*)w5l;
  const float4* W54 = (const float4*)W5;
  for (int i = tid; i < 5 * 1024; i += 256) w54[i] = W54[i];
  __syncthreads();

  const int row0 = blockIdx.x * 16 + w * 4;  // one wave owns 4 rows
  for (int rr = 0; rr < 4; ++rr) {
    const int row = row0 + rr;
    const float h0 = haar[(size_t)row * 5 + 0];
    const float h1 = haar[(size_t)row * 5 + 1];
    const float h2 = haar[(size_t)row * 5 + 2];
    const float h3 = haar[(size_t)row * 5 + 3];
    const float h4 = haar[(size_t)row * 5 + 4];
    const ushort4* ybr = (const ushort4*)(ybf + (size_t)row * OUTDIM);
    const float4* yfr = (const float4*)(out + (size_t)row * OUTDIM);

    float4 vals[16];
    float s = 0.f, s2 = 0.f;
#pragma unroll
    for (int k = 0; k < 16; ++k) {
      int i4 = lane + k * 64;
      float4 d;
      if constexpr (RB) {
        ushort4 u = ybr[i4];
        d.x = bf2f(u.x); d.y = bf2f(u.y); d.z = bf2f(u.z); d.w = bf2f(u.w);
      } else {
        d = yfr[i4];
      }
      float4 cv = ((const float4*)cvec)[i4];
      float4 w0 = w54[0 * 1024 + i4];
      float4 w1 = w54[1 * 1024 + i4];
      float4 w2 = w54[2 * 1024 + i4];
      float4 w3 = w54[3 * 1024 + i4];
      float4 w4 = w54[4 * 1024 + i4];
      float4 t;
      t.x = d.x + cv.x + h0 * w0.x + h1 * w1.x + h2 * w2.x + h3 * w3.x + h4 * w4.x;
      t.y = d.y + cv.y + h0 * w0.y + h1 * w1.y + h2 * w2.y + h3 * w3.y + h4 * w4.y;
      t.z = d.z + cv.z + h0 * w0.z + h1 * w1.z + h2 * w2.z + h3 * w3.z + h4 * w4.z;
      t.w = d.w + cv.w + h0 * w0.w + h1 * w1.w + h2 * w2.w + h3 * w3.w + h4 * w4.w;
      vals[k] = t;
      s += t.x + t.y + t.z + t.w;
      s2 += t.x * t.x + t.y * t.y + t.z * t.z + t.w * t.w;
    }
    // butterfly: every lane ends with the row totals (no LDS, no barrier)
#pragma unroll
    for (int off = 32; off; off >>= 1) {
      s += __shfl_xor(s, off, 64);
      s2 += __shfl_xor(s2, off, 64);
    }
    const float mu = s / (float)OUTDIM;
    const float inv = rsqrtf(s2 / (float)OUTDIM - mu * mu + 1e-5f);
    float4* yo = (float4*)(out + (size_t)row * OUTDIM);
#pragma unroll
    for (int k = 0; k < 16; ++k) {
      int i4 = lane + k * 64;
      float4 gg = ((const float4*)g)[i4];
      float4 bb = ((const float4*)beta)[i4];
      float4 t = vals[k];
      float4 o;
      o.x = (t.x - mu) * inv * gg.x + bb.x;
      o.y = (t.y - mu) * inv * gg.y + bb.y;
      o.z = (t.z - mu) * inv * gg.z + bb.z;
      o.w = (t.w - mu) * inv * gg.w + bb.w;
      yo[i4] = o;
    }
  }
}

// ---------------- launch ----------------
extern "C" void kernel_launch(void* const* d_in, const int* in_sizes, int n_in,
                              void* d_out, int out_size, void* d_ws, size_t ws_size,
                              hipStream_t stream) {
  const float* x      = (const float*)d_in[0];
  const float* lin_w  = (const float*)d_in[1];
  const float* lin_b  = (const float*)d_in[2];
  const float* proj_w = (const float*)d_in[3];
  const float* proj_b = (const float*)d_in[4];
  const float* scales = (const float*)d_in[5];
  const float* trans  = (const float*)d_in[6];
  const float* comb_w = (const float*)d_in[7];
  const float* comb_b = (const float*)d_in[8];
  const float* ln_g   = (const float*)d_in[9];
  const float* ln_b   = (const float*)d_in[10];
  float* out = (float*)d_out;

  char* ws = (char*)d_ws;
  uint16_t* xb   = (uint16_t*)ws;                               // 67,108,864 B
  uint16_t* wb   = (uint16_t*)(ws + 67108864);                  // 33,554,432 B
  float*    haar = (float*)(ws + 100663296);                    // 163,840 B
  float*    cvec = (float*)(ws + 100827136);                    // 16,384 B
  float*    W5   = (float*)(ws + 100843520);                    // 81,920 B
  uint16_t* ybf  = (uint16_t*)(ws + 100925440);                 // 67,108,864 B
  const bool bf16y = ws_size >= 168034304ull;                   // ybf fits?

  hipFuncSetAttribute((const void*)k_gemm<true>,
                      hipFuncAttributeMaxDynamicSharedMemorySize, 131072);
  hipFuncSetAttribute((const void*)k_gemm<false>,
                      hipFuncAttributeMaxDynamicSharedMemorySize, 131072);

  k_pre<<<1025, 256, 0, stream>>>(x, lin_w, proj_w, proj_b, scales, trans,
                                  lin_b, comb_w, comb_b, xb, wb, haar, cvec, W5);
  if (bf16y) {
    k_gemm<true><<<(BDIM / 256) * (OUTDIM / 256), 512, 131072, stream>>>(
        xb, wb, out, ybf);
    k_ln<true><<<BDIM / 16, 256, 0, stream>>>(out, ybf, haar, cvec, W5, ln_g, ln_b);
  } else {
    k_gemm<false><<<(BDIM / 256) * (OUTDIM / 256), 512, 131072, stream>>>(
        xb, wb, out, ybf);
    k_ln<false><<<BDIM / 16, 256, 0, stream>>>(out, ybf, haar, cvec, W5, ln_g, ln_b);
  }
}

// Round 10
// 344.222 us; speedup vs baseline: 1.4392x; 1.4392x over previous
//
#include <hip/hip_runtime.h>
#include <hip/hip_bf16.h>
#include <stdint.h>

// Problem dims (fixed)
constexpr int BDIM = 8192;
constexpr int INDIM = 4096;
constexpr int OUTDIM = 4096;

typedef __attribute__((ext_vector_type(8))) short bf16x8;
typedef __attribute__((ext_vector_type(8))) short short8;
typedef __attribute__((ext_vector_type(4))) float f32x4;

__device__ __forceinline__ uint16_t f2bf_rne(float f) {
  union { float f; uint32_t u; } v; v.f = f;
  uint32_t r = v.u + 0x7fffu + ((v.u >> 16) & 1u);
  return (uint16_t)(r >> 16);
}
__device__ __forceinline__ float bf2f(uint16_t h) {
  union { uint32_t u; float f; } v; v.u = ((uint32_t)h) << 16; return v.f;
}

__device__ __forceinline__ void gload_lds16(const void* g, void* l) {
  __builtin_amdgcn_global_load_lds(
      (const __attribute__((address_space(1))) void*)g,
      (__attribute__((address_space(3))) void*)l, 16, 0, 0);
}

// ---------------- kernel 1: fused pre-pass (4 rows/block, register reuse) ----
// blocks 0..2047    : x -> bf16 + haar (4 rows each; proj_w loads amortized 4x)
// blocks 2048..4095 : lin_w -> bf16 (grid-stride)
// block  4096       : db scalars -> cvec[4096], W5[5][4096]
__global__ __launch_bounds__(256) void k_pre(
    const float* __restrict__ x, const float* __restrict__ lin_w,
    const float* __restrict__ proj_w, const float* __restrict__ proj_b,
    const float* __restrict__ scales, const float* __restrict__ trans,
    const float* __restrict__ lin_b, const float* __restrict__ comb_w,
    const float* __restrict__ comb_b, uint16_t* __restrict__ xb,
    uint16_t* __restrict__ wb, float* __restrict__ haar,
    float* __restrict__ cvec, float* __restrict__ W5) {
  __shared__ float sh[96];  // wred scratch (tiny -> full occupancy)
  const int tid = threadIdx.x;
  const int lane = tid & 63, w = tid >> 6;

  if (blockIdx.x < 2048) {
    const int row0 = blockIdx.x * 4;
    const float4* xr0 = (const float4*)(x + (size_t)(row0 + 0) * INDIM);
    const float4* xr1 = (const float4*)(x + (size_t)(row0 + 1) * INDIM);
    const float4* xr2 = (const float4*)(x + (size_t)(row0 + 2) * INDIM);
    const float4* xr3 = (const float4*)(x + (size_t)(row0 + 3) * INDIM);
    ushort4* xb0 = (ushort4*)(xb + (size_t)(row0 + 0) * INDIM);
    ushort4* xb1 = (ushort4*)(xb + (size_t)(row0 + 1) * INDIM);
    ushort4* xb2 = (ushort4*)(xb + (size_t)(row0 + 2) * INDIM);
    ushort4* xb3 = (ushort4*)(xb + (size_t)(row0 + 3) * INDIM);
    const float4* pw4 = (const float4*)proj_w;
    float acc[4][5];
#pragma unroll
    for (int r = 0; r < 4; ++r)
#pragma unroll
      for (int j = 0; j < 5; ++j) acc[r][j] = 0.f;

#pragma unroll
    for (int c = 0; c < 4; ++c) {
      const int i4 = tid + c * 256;  // wave-interleaved, coalesced
      float4 p[5];
#pragma unroll
      for (int j = 0; j < 5; ++j) p[j] = pw4[j * 1024 + i4];
      const float4* xr[4] = {xr0, xr1, xr2, xr3};
      ushort4* xo[4] = {xb0, xb1, xb2, xb3};
#pragma unroll
      for (int r = 0; r < 4; ++r) {
        float4 v = xr[r][i4];
        ushort4 o;
        o.x = f2bf_rne(v.x); o.y = f2bf_rne(v.y);
        o.z = f2bf_rne(v.z); o.w = f2bf_rne(v.w);
        xo[r][i4] = o;
#pragma unroll
        for (int j = 0; j < 5; ++j)
          acc[r][j] += v.x * p[j].x + v.y * p[j].y + v.z * p[j].z + v.w * p[j].w;
      }
    }
    // wave reduce -> cross-wave via tiny LDS
#pragma unroll
    for (int r = 0; r < 4; ++r)
#pragma unroll
      for (int j = 0; j < 5; ++j) {
        float v = acc[r][j];
#pragma unroll
        for (int off = 32; off; off >>= 1) v += __shfl_down(v, off, 64);
        if (lane == 0) sh[(w * 4 + r) * 5 + j] = v;
      }
    __syncthreads();
    if (tid < 20) {
      const int r = tid / 5, j = tid % 5;
      float pv = sh[(0 * 4 + r) * 5 + j] + sh[(1 * 4 + r) * 5 + j] +
                 sh[(2 * 4 + r) * 5 + j] + sh[(3 * 4 + r) * 5 + j] + proj_b[j];
      float sx = (pv - trans[j]) / scales[j];
      float h = 0.f;
      if (sx >= 0.f && sx < 0.5f) h = 1.f;
      else if (sx >= 0.5f && sx < 1.f) h = -1.f;
      haar[(size_t)(row0 + r) * 5 + j] = h;
    }
  } else if (blockIdx.x < 4096) {
    const int bid = blockIdx.x - 2048;
    const int n8 = (OUTDIM * INDIM) / 8;
    const float4* w4 = (const float4*)lin_w;
    short8* wb8 = (short8*)wb;
    for (int i = bid * 256 + tid; i < n8; i += 2048 * 256) {
      float4 v0 = w4[i * 2];
      float4 v1 = w4[i * 2 + 1];
      short8 o;
      o[0] = (short)f2bf_rne(v0.x); o[1] = (short)f2bf_rne(v0.y);
      o[2] = (short)f2bf_rne(v0.z); o[3] = (short)f2bf_rne(v0.w);
      o[4] = (short)f2bf_rne(v1.x); o[5] = (short)f2bf_rne(v1.y);
      o[6] = (short)f2bf_rne(v1.z); o[7] = (short)f2bf_rne(v1.w);
      wb8[i] = o;
    }
  } else {
    // ---- db scalars -> cvec, W5 (single block) ----
    float* wred = sh;        // [4][11]
    float* dbs = sh + 64;    // [11]
    float acc[11];
#pragma unroll
    for (int j = 0; j < 11; ++j) acc[j] = 0.f;
    for (int r = 0; r < 4; ++r) {
      const float4* xr = (const float4*)(x + (size_t)r * INDIM);
      for (int c = tid; c < INDIM / 4; c += 256) {
        float4 v = xr[c];
#pragma unroll
        for (int j = 0; j < 11; ++j) {
          float4 p = ((const float4*)(proj_w + (size_t)(j + 5) * INDIM))[c];
          acc[j] += v.x * p.x + v.y * p.y + v.z * p.z + v.w * p.w;
        }
      }
    }
#pragma unroll
    for (int j = 0; j < 11; ++j) {
      float v = acc[j];
#pragma unroll
      for (int off = 32; off; off >>= 1) v += __shfl_down(v, off, 64);
      if (lane == 0) wred[w * 11 + j] = v;
    }
    __syncthreads();
    if (tid == 0) {
      const float DB2[4] = {-0.1294095225512604f, -0.2241438680420134f,
                            0.8365163037378079f, -0.4829629131445341f};
      const float DB4[8] = {-0.0074578275060427f, -0.0233534968567756f,
                            0.0218081502370024f,  0.1323683939878645f,
                            -0.0197721859913265f, -0.4461007108737368f,
                            0.5055922216746659f,  -0.1629171572809054f};
      for (int j = 0; j < 11; ++j) {
        float sum = wred[0 * 11 + j] + wred[1 * 11 + j] + wred[2 * 11 + j] +
                    wred[3 * 11 + j];
        float val = sum * 0.25f + proj_b[j + 5];
        float sc = scales[j + 5];
        float sf = 2.f / (1.f + expf(-sc));
        const float* filt = (j < 5) ? DB2 : DB4;
        int L = (j < 5) ? 4 : 8;
        float ssin = 0.f, sabs = 0.f;
        for (int i = 0; i < L; ++i) {
          float fi = filt[i] * sf;
          ssin += sinf(fi * 5.0f);
          sabs += fabsf(fi);
        }
        dbs[j] = val * (ssin / (float)L) / (sabs * 0.1f);
      }
    }
    __syncthreads();
    for (int o = tid; o < OUTDIM; o += 256) {
      const float* cw = comb_w + (size_t)o * 16;
      float cc = lin_b[o] + comb_b[o];
#pragma unroll
      for (int j = 0; j < 11; ++j) cc += dbs[j] * cw[5 + j];
      cvec[o] = cc;
#pragma unroll
      for (int j = 0; j < 5; ++j) W5[j * OUTDIM + o] = cw[j];
    }
  }
}

// ---------------- kernel 4: bf16 MFMA GEMM, 256x256 8-phase (R4 core, FROZEN) ----
// Template WB: epilogue writes bf16 y to Ybf (ws) instead of fp32 to C.

#define BARX() __builtin_amdgcn_s_barrier()
#define LGKM0() do { asm volatile("s_waitcnt lgkmcnt(0)" ::: "memory"); \
                     __builtin_amdgcn_sched_barrier(0); } while (0)
#define VM6() asm volatile("s_waitcnt vmcnt(6)" ::: "memory")

#define STAGE_A(t, q) do { \
  const char* _s = aSrc + (size_t)(q) * 64 * 8192 + (size_t)((t) & 63) * 128; \
  char* _l = sA + ((t) & 1) * 32768 + (q) * 8192 + ldsStage; \
  gload_lds16(_s, _l); gload_lds16(_s + 128 * 8192, _l + 16384); } while (0)

#define STAGE_B(t, h) do { \
  const char* _s = bSrc + (size_t)(h) * 128 * 8192 + (size_t)((t) & 63) * 128; \
  char* _l = sB + ((t) & 1) * 32768 + (h) * 16384 + ldsStage; \
  gload_lds16(_s, _l); gload_lds16(_s + 64 * 8192, _l + 8192); } while (0)

#define RDA4(buf, mb) do { const char* _p = sA + (buf) * 32768; \
  _Pragma("unroll") for (int _m = 0; _m < 4; ++_m) { \
    ar[_m][0] = *(const bf16x8*)(_p + (aoff + ((mb) + _m) * 2048)); \
    ar[_m][1] = *(const bf16x8*)(_p + ((aoff ^ 64) + ((mb) + _m) * 2048)); } } while (0)

#define RDB2(buf, arr, nb) do { const char* _p = sB + (buf) * 32768; \
  _Pragma("unroll") for (int _n = 0; _n < 2; ++_n) { \
    arr[_n][0] = *(const bf16x8*)(_p + (boff + ((nb) + _n) * 2048)); \
    arr[_n][1] = *(const bf16x8*)(_p + ((boff ^ 64) + ((nb) + _n) * 2048)); } } while (0)

#define MF8(mb, arrB, nb) do { \
  __builtin_amdgcn_s_setprio(1); \
  _Pragma("unroll") for (int _m = 0; _m < 4; ++_m) \
  _Pragma("unroll") for (int _n = 0; _n < 2; ++_n) { \
    acc[(mb) + _m][(nb) + _n] = __builtin_amdgcn_mfma_f32_16x16x32_bf16( \
        ar[_m][0], arrB[_n][0], acc[(mb) + _m][(nb) + _n], 0, 0, 0); \
    acc[(mb) + _m][(nb) + _n] = __builtin_amdgcn_mfma_f32_16x16x32_bf16( \
        ar[_m][1], arrB[_n][1], acc[(mb) + _m][(nb) + _n], 0, 0, 0); } \
  __builtin_amdgcn_s_setprio(0); } while (0)

template <bool WB>
__global__ __launch_bounds__(512, 2) void k_gemm(const uint16_t* __restrict__ A,
                                                 const uint16_t* __restrict__ Bw,
                                                 float* __restrict__ C,
                                                 uint16_t* __restrict__ Ybf) {
  constexpr int K = INDIM;   // 4096, row = 8192 bytes
  constexpr int N = OUTDIM;  // 4096
  extern __shared__ char smem[];
  char* sA = smem;
  char* sB = smem + 65536;

  const int tid = threadIdx.x;
  const int wid = tid >> 6;
  const int lane = tid & 63;
  const int l15 = lane & 15;
  const int kh = lane >> 4;
  const int wm = wid >> 2;
  const int wn = wid & 3;

  const int nwg = gridDim.x;
  const int bid = blockIdx.x;
  const int wg = (bid & 7) * (nwg >> 3) + (bid >> 3);
  constexpr int NBN = N / 256;
  const int mblk = wg / NBN, nblk = wg % NBN;
  const size_t arow = (size_t)mblk * 256, brow = (size_t)nblk * 256;

  const int srow = tid >> 3;
  const int scol = ((tid & 7) * 16) ^ ((srow & 7) << 4);
  const char* aSrc = (const char*)A + (arow + srow) * 8192 + scol;
  const char* bSrc = (const char*)Bw + (brow + srow) * 8192 + scol;
  const int ldsStage = wid * 1024;

  const int col0 = (kh * 16) ^ ((l15 & 7) << 4);
  const int aoff = (wm * 128 + l15) * 128 + col0;
  const int boff = (wn * 64 + l15) * 128 + col0;

  f32x4 acc[8][4];
#pragma unroll
  for (int m = 0; m < 8; ++m)
#pragma unroll
    for (int n = 0; n < 4; ++n) acc[m][n] = (f32x4){0.f, 0.f, 0.f, 0.f};
  bf16x8 ar[4][2], b01[2][2], b23[2][2];

  STAGE_A(0, 0); STAGE_A(0, 1); STAGE_B(0, 0); STAGE_B(0, 1);
  STAGE_A(1, 0); STAGE_B(1, 0); STAGE_B(1, 1);
  VM6(); BARX();

  for (int it = 0; it < K / 128; ++it) {
    const int t1 = it * 2 + 1, t2 = it * 2 + 2, t3 = it * 2 + 3;
    // P1
    RDA4(0, 0); RDB2(0, b01, 0);
    STAGE_A(t1, 1);
    BARX(); LGKM0(); MF8(0, b01, 0); BARX();
    // P2
    RDB2(0, b23, 2);
    STAGE_A(t2, 0);
    BARX(); LGKM0(); MF8(0, b23, 2); BARX();
    // P3
    RDA4(0, 4);
    STAGE_B(t2, 0);
    BARX(); LGKM0(); MF8(4, b01, 0); BARX();
    // P4
    STAGE_B(t2, 1);
    BARX(); LGKM0(); MF8(4, b23, 2);
    VM6(); BARX();
    // P5
    RDA4(1, 0); RDB2(1, b01, 0);
    STAGE_A(t2, 1);
    BARX(); LGKM0(); MF8(0, b01, 0); BARX();
    // P6
    RDB2(1, b23, 2);
    STAGE_A(t3, 0);
    BARX(); LGKM0(); MF8(0, b23, 2); BARX();
    // P7
    RDA4(1, 4);
    STAGE_B(t3, 0);
    BARX(); LGKM0(); MF8(4, b01, 0); BARX();
    // P8
    STAGE_B(t3, 1);
    BARX(); LGKM0(); MF8(4, b23, 2);
    VM6(); BARX();
  }

  // epilogue: C/D layout col=lane&15, row=(lane>>4)*4+reg (m89-verified)
  const size_t crow0 = arow + (size_t)wm * 128;
  const int ccol0 = (int)brow + wn * 64;
#pragma unroll
  for (int m = 0; m < 8; ++m) {
#pragma unroll
    for (int n = 0; n < 4; ++n) {
      if constexpr (WB) {
        uint16_t* yp = Ybf + (crow0 + m * 16 + kh * 4) * (size_t)N
                       + ccol0 + n * 16 + l15;
#pragma unroll
        for (int j = 0; j < 4; ++j) yp[(size_t)j * N] = f2bf_rne(acc[m][n][j]);
      } else {
        float* cp = C + (crow0 + m * 16 + kh * 4) * N + ccol0 + n * 16 + l15;
#pragma unroll
        for (int j = 0; j < 4; ++j) cp[(size_t)j * N] = acc[m][n][j];
      }
    }
  }
}

// ---------------- kernel 5: wave-path add + LayerNorm (4 rows/block, reg reuse) ----
// RB: read y as bf16 (ushort4, coalesced); !RB: fp32 from out.
template <bool RB>
__global__ __launch_bounds__(256) void k_ln(
    float* __restrict__ out, const uint16_t* __restrict__ ybf,
    const float* __restrict__ haar, const float* __restrict__ cvec,
    const float* __restrict__ W5, const float* __restrict__ g,
    const float* __restrict__ beta) {
  const int tid = threadIdx.x, lane = tid & 63, w = tid >> 6;
  const int row0 = blockIdx.x * 4;
  float h[4][5];
#pragma unroll
  for (int r = 0; r < 4; ++r)
#pragma unroll
    for (int j = 0; j < 5; ++j) h[r][j] = haar[(size_t)(row0 + r) * 5 + j];

  const ushort4* yb[4];
  const float4* yf[4];
  float4* yo[4];
#pragma unroll
  for (int r = 0; r < 4; ++r) {
    yb[r] = (const ushort4*)(ybf + (size_t)(row0 + r) * OUTDIM);
    yf[r] = (const float4*)(out + (size_t)(row0 + r) * OUTDIM);
    yo[r] = (float4*)(out + (size_t)(row0 + r) * OUTDIM);
  }

  float4 vals[4][4];
  float s[4] = {0.f, 0.f, 0.f, 0.f}, s2[4] = {0.f, 0.f, 0.f, 0.f};
#pragma unroll
  for (int c = 0; c < 4; ++c) {
    const int i4 = tid + c * 256;  // wave-interleaved, coalesced
    float4 cv = ((const float4*)cvec)[i4];
    float4 w0 = ((const float4*)(W5 + 0 * OUTDIM))[i4];
    float4 w1 = ((const float4*)(W5 + 1 * OUTDIM))[i4];
    float4 w2 = ((const float4*)(W5 + 2 * OUTDIM))[i4];
    float4 w3 = ((const float4*)(W5 + 3 * OUTDIM))[i4];
    float4 w4 = ((const float4*)(W5 + 4 * OUTDIM))[i4];
#pragma unroll
    for (int r = 0; r < 4; ++r) {
      float4 d;
      if constexpr (RB) {
        ushort4 u = yb[r][i4];
        d.x = bf2f(u.x); d.y = bf2f(u.y); d.z = bf2f(u.z); d.w = bf2f(u.w);
      } else {
        d = yf[r][i4];
      }
      float4 t;
      t.x = d.x + cv.x + h[r][0]*w0.x + h[r][1]*w1.x + h[r][2]*w2.x + h[r][3]*w3.x + h[r][4]*w4.x;
      t.y = d.y + cv.y + h[r][0]*w0.y + h[r][1]*w1.y + h[r][2]*w2.y + h[r][3]*w3.y + h[r][4]*w4.y;
      t.z = d.z + cv.z + h[r][0]*w0.z + h[r][1]*w1.z + h[r][2]*w2.z + h[r][3]*w3.z + h[r][4]*w4.z;
      t.w = d.w + cv.w + h[r][0]*w0.w + h[r][1]*w1.w + h[r][2]*w2.w + h[r][3]*w3.w + h[r][4]*w4.w;
      vals[r][c] = t;
      s[r] += t.x + t.y + t.z + t.w;
      s2[r] += t.x * t.x + t.y * t.y + t.z * t.z + t.w * t.w;
    }
  }

  __shared__ float rs[4][4], rs2[4][4];  // [wave][row]
#pragma unroll
  for (int r = 0; r < 4; ++r) {
    float a = s[r], b = s2[r];
#pragma unroll
    for (int off = 32; off; off >>= 1) {
      a += __shfl_down(a, off, 64);
      b += __shfl_down(b, off, 64);
    }
    if (lane == 0) { rs[w][r] = a; rs2[w][r] = b; }
  }
  __syncthreads();
  float mu[4], inv[4];
#pragma unroll
  for (int r = 0; r < 4; ++r) {
    float S = rs[0][r] + rs[1][r] + rs[2][r] + rs[3][r];
    float S2 = rs2[0][r] + rs2[1][r] + rs2[2][r] + rs2[3][r];
    mu[r] = S / (float)OUTDIM;
    inv[r] = rsqrtf(S2 / (float)OUTDIM - mu[r] * mu[r] + 1e-5f);
  }
#pragma unroll
  for (int c = 0; c < 4; ++c) {
    const int i4 = tid + c * 256;
    float4 gg = ((const float4*)g)[i4];
    float4 bb = ((const float4*)beta)[i4];
#pragma unroll
    for (int r = 0; r < 4; ++r) {
      float4 t = vals[r][c];
      float4 o;
      o.x = (t.x - mu[r]) * inv[r] * gg.x + bb.x;
      o.y = (t.y - mu[r]) * inv[r] * gg.y + bb.y;
      o.z = (t.z - mu[r]) * inv[r] * gg.z + bb.z;
      o.w = (t.w - mu[r]) * inv[r] * gg.w + bb.w;
      yo[r][i4] = o;
    }
  }
}

// ---------------- launch ----------------
extern "C" void kernel_launch(void* const* d_in, const int* in_sizes, int n_in,
                              void* d_out, int out_size, void* d_ws, size_t ws_size,
                              hipStream_t stream) {
  const float* x      = (const float*)d_in[0];
  const float* lin_w  = (const float*)d_in[1];
  const float* lin_b  = (const float*)d_in[2];
  const float* proj_w = (const float*)d_in[3];
  const float* proj_b = (const float*)d_in[4];
  const float* scales = (const float*)d_in[5];
  const float* trans  = (const float*)d_in[6];
  const float* comb_w = (const float*)d_in[7];
  const float* comb_b = (const float*)d_in[8];
  const float* ln_g   = (const float*)d_in[9];
  const float* ln_b   = (const float*)d_in[10];
  float* out = (float*)d_out;

  char* ws = (char*)d_ws;
  uint16_t* xb   = (uint16_t*)ws;                               // 67,108,864 B
  uint16_t* wb   = (uint16_t*)(ws + 67108864);                  // 33,554,432 B
  float*    haar = (float*)(ws + 100663296);                    // 163,840 B
  float*    cvec = (float*)(ws + 100827136);                    // 16,384 B
  float*    W5   = (float*)(ws + 100843520);                    // 81,920 B
  uint16_t* ybf  = (uint16_t*)(ws + 100925440);                 // 67,108,864 B
  const bool bf16y = ws_size >= 168034304ull;                   // ybf fits?

  hipFuncSetAttribute((const void*)k_gemm<true>,
                      hipFuncAttributeMaxDynamicSharedMemorySize, 131072);
  hipFuncSetAttribute((const void*)k_gemm<false>,
                      hipFuncAttributeMaxDynamicSharedMemorySize, 131072);

  k_pre<<<4097, 256, 0, stream>>>(x, lin_w, proj_w, proj_b, scales, trans,
                                  lin_b, comb_w, comb_b, xb, wb, haar, cvec, W5);
  if (bf16y) {
    k_gemm<true><<<(BDIM / 256) * (OUTDIM / 256), 512, 131072, stream>>>(
        xb, wb, out, ybf);
    k_ln<true><<<BDIM / 4, 256, 0, stream>>>(out, ybf, haar, cvec, W5, ln_g, ln_b);
  } else {
    k_gemm<false><<<(BDIM / 256) * (OUTDIM / 256), 512, 131072, stream>>>(
        xb, wb, out, ybf);
    k_ln<false><<<BDIM / 4, 256, 0, stream>>>(out, ybf, haar, cvec, W5, ln_g, ln_b);
  }
}

// Round 11
// 338.013 us; speedup vs baseline: 1.4656x; 1.0184x over previous
//
#include <hip/hip_runtime.h>
#include <hip/hip_bf16.h>
#include <stdint.h>

// Problem dims (fixed)
constexpr int BDIM = 8192;
constexpr int INDIM = 4096;
constexpr int OUTDIM = 4096;

typedef __attribute__((ext_vector_type(8))) short bf16x8;
typedef __attribute__((ext_vector_type(8))) short short8;
typedef __attribute__((ext_vector_type(4))) float f32x4;

__device__ __forceinline__ uint16_t f2bf_rne(float f) {
  union { float f; uint32_t u; } v; v.f = f;
  uint32_t r = v.u + 0x7fffu + ((v.u >> 16) & 1u);
  return (uint16_t)(r >> 16);
}
__device__ __forceinline__ float bf2f(uint16_t h) {
  union { uint32_t u; float f; } v; v.u = ((uint32_t)h) << 16; return v.f;
}

__device__ __forceinline__ void gload_lds16(const void* g, void* l) {
  __builtin_amdgcn_global_load_lds(
      (const __attribute__((address_space(1))) void*)g,
      (__attribute__((address_space(3))) void*)l, 16, 0, 0);
}

// ---------------- kernel 1: fused pre-pass (4 rows/block, register reuse) ----
__global__ __launch_bounds__(256) void k_pre(
    const float* __restrict__ x, const float* __restrict__ lin_w,
    const float* __restrict__ proj_w, const float* __restrict__ proj_b,
    const float* __restrict__ scales, const float* __restrict__ trans,
    const float* __restrict__ lin_b, const float* __restrict__ comb_w,
    const float* __restrict__ comb_b, uint16_t* __restrict__ xb,
    uint16_t* __restrict__ wb, float* __restrict__ haar,
    float* __restrict__ cvec, float* __restrict__ W5) {
  __shared__ float sh[96];
  const int tid = threadIdx.x;
  const int lane = tid & 63, w = tid >> 6;

  if (blockIdx.x < 2048) {
    const int row0 = blockIdx.x * 4;
    const float4* xr0 = (const float4*)(x + (size_t)(row0 + 0) * INDIM);
    const float4* xr1 = (const float4*)(x + (size_t)(row0 + 1) * INDIM);
    const float4* xr2 = (const float4*)(x + (size_t)(row0 + 2) * INDIM);
    const float4* xr3 = (const float4*)(x + (size_t)(row0 + 3) * INDIM);
    ushort4* xb0 = (ushort4*)(xb + (size_t)(row0 + 0) * INDIM);
    ushort4* xb1 = (ushort4*)(xb + (size_t)(row0 + 1) * INDIM);
    ushort4* xb2 = (ushort4*)(xb + (size_t)(row0 + 2) * INDIM);
    ushort4* xb3 = (ushort4*)(xb + (size_t)(row0 + 3) * INDIM);
    const float4* pw4 = (const float4*)proj_w;
    float acc[4][5];
#pragma unroll
    for (int r = 0; r < 4; ++r)
#pragma unroll
      for (int j = 0; j < 5; ++j) acc[r][j] = 0.f;

#pragma unroll
    for (int c = 0; c < 4; ++c) {
      const int i4 = tid + c * 256;
      float4 p[5];
#pragma unroll
      for (int j = 0; j < 5; ++j) p[j] = pw4[j * 1024 + i4];
      const float4* xr[4] = {xr0, xr1, xr2, xr3};
      ushort4* xo[4] = {xb0, xb1, xb2, xb3};
#pragma unroll
      for (int r = 0; r < 4; ++r) {
        float4 v = xr[r][i4];
        ushort4 o;
        o.x = f2bf_rne(v.x); o.y = f2bf_rne(v.y);
        o.z = f2bf_rne(v.z); o.w = f2bf_rne(v.w);
        xo[r][i4] = o;
#pragma unroll
        for (int j = 0; j < 5; ++j)
          acc[r][j] += v.x * p[j].x + v.y * p[j].y + v.z * p[j].z + v.w * p[j].w;
      }
    }
#pragma unroll
    for (int r = 0; r < 4; ++r)
#pragma unroll
      for (int j = 0; j < 5; ++j) {
        float v = acc[r][j];
#pragma unroll
        for (int off = 32; off; off >>= 1) v += __shfl_down(v, off, 64);
        if (lane == 0) sh[(w * 4 + r) * 5 + j] = v;
      }
    __syncthreads();
    if (tid < 20) {
      const int r = tid / 5, j = tid % 5;
      float pv = sh[(0 * 4 + r) * 5 + j] + sh[(1 * 4 + r) * 5 + j] +
                 sh[(2 * 4 + r) * 5 + j] + sh[(3 * 4 + r) * 5 + j] + proj_b[j];
      float sx = (pv - trans[j]) / scales[j];
      float h = 0.f;
      if (sx >= 0.f && sx < 0.5f) h = 1.f;
      else if (sx >= 0.5f && sx < 1.f) h = -1.f;
      haar[(size_t)(row0 + r) * 5 + j] = h;
    }
  } else if (blockIdx.x < 4096) {
    const int bid = blockIdx.x - 2048;
    const int n8 = (OUTDIM * INDIM) / 8;
    const float4* w4 = (const float4*)lin_w;
    short8* wb8 = (short8*)wb;
    for (int i = bid * 256 + tid; i < n8; i += 2048 * 256) {
      float4 v0 = w4[i * 2];
      float4 v1 = w4[i * 2 + 1];
      short8 o;
      o[0] = (short)f2bf_rne(v0.x); o[1] = (short)f2bf_rne(v0.y);
      o[2] = (short)f2bf_rne(v0.z); o[3] = (short)f2bf_rne(v0.w);
      o[4] = (short)f2bf_rne(v1.x); o[5] = (short)f2bf_rne(v1.y);
      o[6] = (short)f2bf_rne(v1.z); o[7] = (short)f2bf_rne(v1.w);
      wb8[i] = o;
    }
  } else {
    float* wred = sh;
    float* dbs = sh + 64;
    float acc[11];
#pragma unroll
    for (int j = 0; j < 11; ++j) acc[j] = 0.f;
    for (int r = 0; r < 4; ++r) {
      const float4* xr = (const float4*)(x + (size_t)r * INDIM);
      for (int c = tid; c < INDIM / 4; c += 256) {
        float4 v = xr[c];
#pragma unroll
        for (int j = 0; j < 11; ++j) {
          float4 p = ((const float4*)(proj_w + (size_t)(j + 5) * INDIM))[c];
          acc[j] += v.x * p.x + v.y * p.y + v.z * p.z + v.w * p.w;
        }
      }
    }
#pragma unroll
    for (int j = 0; j < 11; ++j) {
      float v = acc[j];
#pragma unroll
      for (int off = 32; off; off >>= 1) v += __shfl_down(v, off, 64);
      if (lane == 0) wred[w * 11 + j] = v;
    }
    __syncthreads();
    if (tid == 0) {
      const float DB2[4] = {-0.1294095225512604f, -0.2241438680420134f,
                            0.8365163037378079f, -0.4829629131445341f};
      const float DB4[8] = {-0.0074578275060427f, -0.0233534968567756f,
                            0.0218081502370024f,  0.1323683939878645f,
                            -0.0197721859913265f, -0.4461007108737368f,
                            0.5055922216746659f,  -0.1629171572809054f};
      for (int j = 0; j < 11; ++j) {
        float sum = wred[0 * 11 + j] + wred[1 * 11 + j] + wred[2 * 11 + j] +
                    wred[3 * 11 + j];
        float val = sum * 0.25f + proj_b[j + 5];
        float sc = scales[j + 5];
        float sf = 2.f / (1.f + expf(-sc));
        const float* filt = (j < 5) ? DB2 : DB4;
        int L = (j < 5) ? 4 : 8;
        float ssin = 0.f, sabs = 0.f;
        for (int i = 0; i < L; ++i) {
          float fi = filt[i] * sf;
          ssin += sinf(fi * 5.0f);
          sabs += fabsf(fi);
        }
        dbs[j] = val * (ssin / (float)L) / (sabs * 0.1f);
      }
    }
    __syncthreads();
    for (int o = tid; o < OUTDIM; o += 256) {
      const float* cw = comb_w + (size_t)o * 16;
      float cc = lin_b[o] + comb_b[o];
#pragma unroll
      for (int j = 0; j < 11; ++j) cc += dbs[j] * cw[5 + j];
      cvec[o] = cc;
#pragma unroll
      for (int j = 0; j < 5; ++j) W5[j * OUTDIM + o] = cw[j];
    }
  }
}

// ---------------- kernel 4: bf16 MFMA GEMM, 256x256 8-phase ----------------
// R11: single barrier per phase, MFMA AFTER the barrier.
// Phase = [RD(p); STAGE(p); lgkm(0); (vmcnt(6) @P4/P8); s_barrier; MFMA(p)]
// WAR safety: every wave drains its own RD before the barrier; a wave racing
// into STAGE(p+1) must first pass that barrier. vmcnt(6)+barrier guards fresh-
// buffer reads (FIFO drains exactly the next-consumed tile, as R4). MFMA is
// register-only, immune to concurrent LDS writes. LGKM0's memory clobber pins
// RD/STAGE ordering (rule 18).

#define BARX() __builtin_amdgcn_s_barrier()
#define LGKM0() do { asm volatile("s_waitcnt lgkmcnt(0)" ::: "memory"); \
                     __builtin_amdgcn_sched_barrier(0); } while (0)
#define VM6() asm volatile("s_waitcnt vmcnt(6)" ::: "memory")

#define STAGE_A(t, q) do { \
  const char* _s = aSrc + (size_t)(q) * 64 * 8192 + (size_t)((t) & 63) * 128; \
  char* _l = sA + ((t) & 1) * 32768 + (q) * 8192 + ldsStage; \
  gload_lds16(_s, _l); gload_lds16(_s + 128 * 8192, _l + 16384); } while (0)

#define STAGE_B(t, h) do { \
  const char* _s = bSrc + (size_t)(h) * 128 * 8192 + (size_t)((t) & 63) * 128; \
  char* _l = sB + ((t) & 1) * 32768 + (h) * 16384 + ldsStage; \
  gload_lds16(_s, _l); gload_lds16(_s + 64 * 8192, _l + 8192); } while (0)

#define RDA4(buf, mb) do { const char* _p = sA + (buf) * 32768; \
  _Pragma("unroll") for (int _m = 0; _m < 4; ++_m) { \
    ar[_m][0] = *(const bf16x8*)(_p + (aoff + ((mb) + _m) * 2048)); \
    ar[_m][1] = *(const bf16x8*)(_p + ((aoff ^ 64) + ((mb) + _m) * 2048)); } } while (0)

#define RDB2(buf, arr, nb) do { const char* _p = sB + (buf) * 32768; \
  _Pragma("unroll") for (int _n = 0; _n < 2; ++_n) { \
    arr[_n][0] = *(const bf16x8*)(_p + (boff + ((nb) + _n) * 2048)); \
    arr[_n][1] = *(const bf16x8*)(_p + ((boff ^ 64) + ((nb) + _n) * 2048)); } } while (0)

#define MF8(mb, arrB, nb) do { \
  __builtin_amdgcn_s_setprio(1); \
  _Pragma("unroll") for (int _m = 0; _m < 4; ++_m) \
  _Pragma("unroll") for (int _n = 0; _n < 2; ++_n) { \
    acc[(mb) + _m][(nb) + _n] = __builtin_amdgcn_mfma_f32_16x16x32_bf16( \
        ar[_m][0], arrB[_n][0], acc[(mb) + _m][(nb) + _n], 0, 0, 0); \
    acc[(mb) + _m][(nb) + _n] = __builtin_amdgcn_mfma_f32_16x16x32_bf16( \
        ar[_m][1], arrB[_n][1], acc[(mb) + _m][(nb) + _n], 0, 0, 0); } \
  __builtin_amdgcn_s_setprio(0); } while (0)

template <bool WB>
__global__ __launch_bounds__(512, 2) void k_gemm(const uint16_t* __restrict__ A,
                                                 const uint16_t* __restrict__ Bw,
                                                 float* __restrict__ C,
                                                 uint16_t* __restrict__ Ybf) {
  constexpr int K = INDIM;   // 4096, row = 8192 bytes
  constexpr int N = OUTDIM;  // 4096
  extern __shared__ char smem[];
  char* sA = smem;
  char* sB = smem + 65536;

  const int tid = threadIdx.x;
  const int wid = tid >> 6;
  const int lane = tid & 63;
  const int l15 = lane & 15;
  const int kh = lane >> 4;
  const int wm = wid >> 2;
  const int wn = wid & 3;

  const int nwg = gridDim.x;
  const int bid = blockIdx.x;
  const int wg = (bid & 7) * (nwg >> 3) + (bid >> 3);
  constexpr int NBN = N / 256;
  const int mblk = wg / NBN, nblk = wg % NBN;
  const size_t arow = (size_t)mblk * 256, brow = (size_t)nblk * 256;

  const int srow = tid >> 3;
  const int scol = ((tid & 7) * 16) ^ ((srow & 7) << 4);
  const char* aSrc = (const char*)A + (arow + srow) * 8192 + scol;
  const char* bSrc = (const char*)Bw + (brow + srow) * 8192 + scol;
  const int ldsStage = wid * 1024;

  const int col0 = (kh * 16) ^ ((l15 & 7) << 4);
  const int aoff = (wm * 128 + l15) * 128 + col0;
  const int boff = (wn * 64 + l15) * 128 + col0;

  f32x4 acc[8][4];
#pragma unroll
  for (int m = 0; m < 8; ++m)
#pragma unroll
    for (int n = 0; n < 4; ++n) acc[m][n] = (f32x4){0.f, 0.f, 0.f, 0.f};
  bf16x8 ar[4][2], b01[2][2], b23[2][2];

  // prologue: t0 full + t1 (Aq0, Blo, Bhi); vmcnt(6) keeps t1's 6 loads,
  // drains all of t0; barrier -> every wave's slices arrived.
  STAGE_A(0, 0); STAGE_A(0, 1); STAGE_B(0, 0); STAGE_B(0, 1);
  STAGE_A(1, 0); STAGE_B(1, 0); STAGE_B(1, 1);
  VM6(); BARX();

  for (int it = 0; it < K / 128; ++it) {
    const int t1 = it * 2 + 1, t2 = it * 2 + 2, t3 = it * 2 + 3;
    // P1: RD buf0 (m0-3, b01); stage t1 A-q1
    RDA4(0, 0); RDB2(0, b01, 0);
    STAGE_A(t1, 1);
    LGKM0(); BARX(); MF8(0, b01, 0);
    // P2: RD b23; stage t2 A-q0 (buf0 A-q0 readers drained before P1's barrier)
    RDB2(0, b23, 2);
    STAGE_A(t2, 0);
    LGKM0(); BARX(); MF8(0, b23, 2);
    // P3: RD m4-7; stage t2 B-lo (buf0 B readers drained before P2's barrier)
    RDA4(0, 4);
    STAGE_B(t2, 0);
    LGKM0(); BARX(); MF8(4, b01, 0);
    // P4: stage t2 B-hi; vmcnt(6) -> t1 fully arrived after this barrier
    STAGE_B(t2, 1);
    LGKM0(); VM6(); BARX(); MF8(4, b23, 2);
    // P5: RD buf1 (t1); stage t2 A-q1
    RDA4(1, 0); RDB2(1, b01, 0);
    STAGE_A(t2, 1);
    LGKM0(); BARX(); MF8(0, b01, 0);
    // P6: stage t3 A-q0
    RDB2(1, b23, 2);
    STAGE_A(t3, 0);
    LGKM0(); BARX(); MF8(0, b23, 2);
    // P7: stage t3 B-lo
    RDA4(1, 4);
    STAGE_B(t3, 0);
    LGKM0(); BARX(); MF8(4, b01, 0);
    // P8: stage t3 B-hi; vmcnt(6) -> t2 fully arrived after this barrier
    STAGE_B(t3, 1);
    LGKM0(); VM6(); BARX(); MF8(4, b23, 2);
  }

  // epilogue: C/D layout col=lane&15, row=(lane>>4)*4+reg (m89-verified)
  const size_t crow0 = arow + (size_t)wm * 128;
  const int ccol0 = (int)brow + wn * 64;
#pragma unroll
  for (int m = 0; m < 8; ++m) {
#pragma unroll
    for (int n = 0; n < 4; ++n) {
      if constexpr (WB) {
        uint16_t* yp = Ybf + (crow0 + m * 16 + kh * 4) * (size_t)N
                       + ccol0 + n * 16 + l15;
#pragma unroll
        for (int j = 0; j < 4; ++j) yp[(size_t)j * N] = f2bf_rne(acc[m][n][j]);
      } else {
        float* cp = C + (crow0 + m * 16 + kh * 4) * N + ccol0 + n * 16 + l15;
#pragma unroll
        for (int j = 0; j < 4; ++j) cp[(size_t)j * N] = acc[m][n][j];
      }
    }
  }
}

// ---------------- kernel 5: wave-path add + LayerNorm (4 rows/block, reg reuse) ----
template <bool RB>
__global__ __launch_bounds__(256) void k_ln(
    float* __restrict__ out, const uint16_t* __restrict__ ybf,
    const float* __restrict__ haar, const float* __restrict__ cvec,
    const float* __restrict__ W5, const float* __restrict__ g,
    const float* __restrict__ beta) {
  const int tid = threadIdx.x, lane = tid & 63, w = tid >> 6;
  const int row0 = blockIdx.x * 4;
  float h[4][5];
#pragma unroll
  for (int r = 0; r < 4; ++r)
#pragma unroll
    for (int j = 0; j < 5; ++j) h[r][j] = haar[(size_t)(row0 + r) * 5 + j];

  const ushort4* yb[4];
  const float4* yf[4];
  float4* yo[4];
#pragma unroll
  for (int r = 0; r < 4; ++r) {
    yb[r] = (const ushort4*)(ybf + (size_t)(row0 + r) * OUTDIM);
    yf[r] = (const float4*)(out + (size_t)(row0 + r) * OUTDIM);
    yo[r] = (float4*)(out + (size_t)(row0 + r) * OUTDIM);
  }

  float4 vals[4][4];
  float s[4] = {0.f, 0.f, 0.f, 0.f}, s2[4] = {0.f, 0.f, 0.f, 0.f};
#pragma unroll
  for (int c = 0; c < 4; ++c) {
    const int i4 = tid + c * 256;
    float4 cv = ((const float4*)cvec)[i4];
    float4 w0 = ((const float4*)(W5 + 0 * OUTDIM))[i4];
    float4 w1 = ((const float4*)(W5 + 1 * OUTDIM))[i4];
    float4 w2 = ((const float4*)(W5 + 2 * OUTDIM))[i4];
    float4 w3 = ((const float4*)(W5 + 3 * OUTDIM))[i4];
    float4 w4 = ((const float4*)(W5 + 4 * OUTDIM))[i4];
#pragma unroll
    for (int r = 0; r < 4; ++r) {
      float4 d;
      if constexpr (RB) {
        ushort4 u = yb[r][i4];
        d.x = bf2f(u.x); d.y = bf2f(u.y); d.z = bf2f(u.z); d.w = bf2f(u.w);
      } else {
        d = yf[r][i4];
      }
      float4 t;
      t.x = d.x + cv.x + h[r][0]*w0.x + h[r][1]*w1.x + h[r][2]*w2.x + h[r][3]*w3.x + h[r][4]*w4.x;
      t.y = d.y + cv.y + h[r][0]*w0.y + h[r][1]*w1.y + h[r][2]*w2.y + h[r][3]*w3.y + h[r][4]*w4.y;
      t.z = d.z + cv.z + h[r][0]*w0.z + h[r][1]*w1.z + h[r][2]*w2.z + h[r][3]*w3.z + h[r][4]*w4.z;
      t.w = d.w + cv.w + h[r][0]*w0.w + h[r][1]*w1.w + h[r][2]*w2.w + h[r][3]*w3.w + h[r][4]*w4.w;
      vals[r][c] = t;
      s[r] += t.x + t.y + t.z + t.w;
      s2[r] += t.x * t.x + t.y * t.y + t.z * t.z + t.w * t.w;
    }
  }

  __shared__ float rs[4][4], rs2[4][4];
#pragma unroll
  for (int r = 0; r < 4; ++r) {
    float a = s[r], b = s2[r];
#pragma unroll
    for (int off = 32; off; off >>= 1) {
      a += __shfl_down(a, off, 64);
      b += __shfl_down(b, off, 64);
    }
    if (lane == 0) { rs[w][r] = a; rs2[w][r] = b; }
  }
  __syncthreads();
  float mu[4], inv[4];
#pragma unroll
  for (int r = 0; r < 4; ++r) {
    float S = rs[0][r] + rs[1][r] + rs[2][r] + rs[3][r];
    float S2 = rs2[0][r] + rs2[1][r] + rs2[2][r] + rs2[3][r];
    mu[r] = S / (float)OUTDIM;
    inv[r] = rsqrtf(S2 / (float)OUTDIM - mu[r] * mu[r] + 1e-5f);
  }
#pragma unroll
  for (int c = 0; c < 4; ++c) {
    const int i4 = tid + c * 256;
    float4 gg = ((const float4*)g)[i4];
    float4 bb = ((const float4*)beta)[i4];
#pragma unroll
    for (int r = 0; r < 4; ++r) {
      float4 t = vals[r][c];
      float4 o;
      o.x = (t.x - mu[r]) * inv[r] * gg.x + bb.x;
      o.y = (t.y - mu[r]) * inv[r] * gg.y + bb.y;
      o.z = (t.z - mu[r]) * inv[r] * gg.z + bb.z;
      o.w = (t.w - mu[r]) * inv[r] * gg.w + bb.w;
      yo[r][i4] = o;
    }
  }
}

// ---------------- launch ----------------
extern "C" void kernel_launch(void* const* d_in, const int* in_sizes, int n_in,
                              void* d_out, int out_size, void* d_ws, size_t ws_size,
                              hipStream_t stream) {
  const float* x      = (const float*)d_in[0];
  const float* lin_w  = (const float*)d_in[1];
  const float* lin_b  = (const float*)d_in[2];
  const float* proj_w = (const float*)d_in[3];
  const float* proj_b = (const float*)d_in[4];
  const float* scales = (const float*)d_in[5];
  const float* trans  = (const float*)d_in[6];
  const float* comb_w = (const float*)d_in[7];
  const float* comb_b = (const float*)d_in[8];
  const float* ln_g   = (const float*)d_in[9];
  const float* ln_b   = (const float*)d_in[10];
  float* out = (float*)d_out;

  char* ws = (char*)d_ws;
  uint16_t* xb   = (uint16_t*)ws;                               // 67,108,864 B
  uint16_t* wb   = (uint16_t*)(ws + 67108864);                  // 33,554,432 B
  float*    haar = (float*)(ws + 100663296);                    // 163,840 B
  float*    cvec = (float*)(ws + 100827136);                    // 16,384 B
  float*    W5   = (float*)(ws + 100843520);                    // 81,920 B
  uint16_t* ybf  = (uint16_t*)(ws + 100925440);                 // 67,108,864 B
  const bool bf16y = ws_size >= 168034304ull;                   // ybf fits?

  hipFuncSetAttribute((const void*)k_gemm<true>,
                      hipFuncAttributeMaxDynamicSharedMemorySize, 131072);
  hipFuncSetAttribute((const void*)k_gemm<false>,
                      hipFuncAttributeMaxDynamicSharedMemorySize, 131072);

  k_pre<<<4097, 256, 0, stream>>>(x, lin_w, proj_w, proj_b, scales, trans,
                                  lin_b, comb_w, comb_b, xb, wb, haar, cvec, W5);
  if (bf16y) {
    k_gemm<true><<<(BDIM / 256) * (OUTDIM / 256), 512, 131072, stream>>>(
        xb, wb, out, ybf);
    k_ln<true><<<BDIM / 4, 256, 0, stream>>>(out, ybf, haar, cvec, W5, ln_g, ln_b);
  } else {
    k_gemm<false><<<(BDIM / 256) * (OUTDIM / 256), 512, 131072, stream>>>(
        xb, wb, out, ybf);
    k_ln<false><<<BDIM / 4, 256, 0, stream>>>(out, ybf, haar, cvec, W5, ln_g, ln_b);
  }
}